// Round 7
// baseline (400.968 us; speedup 1.0000x reference)
//
#include <hip/hip_runtime.h>
#include <hip/hip_bf16.h>
#include <hip/hip_fp16.h>

// Problem constants (B=8, T=4096, Din=Dout=256, WINDOW=2)
#define BDIM 8
#define TDIM 4096
#define DDIM 256
#define MDIM (BDIM * TDIM)      // 32768
#define SCHUNK 128              // t per scan block
#define NCH (TDIM / SCHUNK)     // 32 chunks per batch row

typedef _Float16 f16x8 __attribute__((ext_vector_type(8)));
typedef float f32x4 __attribute__((ext_vector_type(4)));

__device__ __forceinline__ float sigmoid_(float x) {
    return 1.0f / (1.0f + __expf(-x));
}
__device__ __forceinline__ float tanh_(float x) {
    return 2.0f / (1.0f + __expf(-2.0f * x)) - 1.0f;
}

__device__ __forceinline__ f16x8 cvt8(const float4 a, const float4 b) {
    f16x8 r;
    r[0] = (_Float16)a.x; r[1] = (_Float16)a.y;
    r[2] = (_Float16)a.z; r[3] = (_Float16)a.w;
    r[4] = (_Float16)b.x; r[5] = (_Float16)b.y;
    r[6] = (_Float16)b.z; r[7] = (_Float16)b.w;
    return r;
}

// ---------------------------------------------------------------------------
// W[g][w][kin][n] fp32 -> Wt[g][n][w*256+kin] f16 (contiguous in k).
// ---------------------------------------------------------------------------
__global__ __launch_bounds__(256) void convert_w(
    const float* __restrict__ Wz, const float* __restrict__ Wf,
    const float* __restrict__ Wo, _Float16* __restrict__ Wt) {
    const int idx = blockIdx.x * 256 + threadIdx.x;  // < 3*2*256*256
    const int n = idx & 255;
    const int kin = (idx >> 8) & 255;
    const int w = (idx >> 16) & 1;
    const int g = idx >> 17;
    const float* W = (g == 0) ? Wz : (g == 1) ? Wf : Wo;
    const float v = W[(size_t)w * 65536 + (size_t)kin * 256 + n];
    Wt[((size_t)g * 256 + n) * 512 + w * 256 + kin] = (_Float16)v;
}

// ---------------------------------------------------------------------------
// MFMA GEMM with register-staged double-buffer pipeline (round-4 kernel,
// best measured 67.8 us — reverted verbatim).
// ---------------------------------------------------------------------------
__global__ __launch_bounds__(256) void gates_mfma(
    const float* __restrict__ x, const _Float16* __restrict__ Wt,
    const float* __restrict__ bz, const float* __restrict__ bfv,
    const float* __restrict__ bo,
    _Float16* __restrict__ zbuf, _Float16* __restrict__ fbuf,
    _Float16* __restrict__ obuf) {
    const int gate = blockIdx.z;
    const int m0 = blockIdx.x * 128;
    const int n0 = blockIdx.y * 128;
    const int tid = threadIdx.x;
    const int lane = tid & 63;
    const int wave = tid >> 6;
    const int wr = wave >> 1;  // wave row (0..1)
    const int wc = wave & 1;   // wave col (0..1)

    // [0,16384): buf0 = A(8K) | B(8K); [16384,32768): buf1.
    // Epilogue reuses [0,40960) as 4 x 10240 B per-wave repack tiles.
    __shared__ __align__(16) char smem[40960];

    // Staging map: thread tid covers LDS row tid>>1, 16 halves at (tid&1)*16.
    const int arow = tid >> 1;        // 0..127
    const int ac = (tid & 1) * 16;    // half offset in the 32-wide k tile

    const int b = m0 >> 12;
    const int t0 = m0 & (TDIM - 1);

    const float* xb = x + (size_t)b * TDIM * DDIM;
    const _Float16* pB = Wt + ((size_t)gate * 256 + n0 + arow) * 512 + ac;

    float4 ga0, ga1, ga2, ga3;
    int4 gb0, gb1;

#define LOAD_TILE(k0)                                                        \
    {                                                                        \
        const int half = (k0) >> 8;                                          \
        const int kin = (k0) & 255;                                          \
        const int t = t0 + arow - 1 + half;                                  \
        if (t >= 0) {                                                        \
            const float* src = xb + (size_t)t * DDIM + kin + ac;             \
            ga0 = *(const float4*)(src);                                     \
            ga1 = *(const float4*)(src + 4);                                 \
            ga2 = *(const float4*)(src + 8);                                 \
            ga3 = *(const float4*)(src + 12);                                \
        } else {                                                             \
            ga0 = ga1 = ga2 = ga3 = make_float4(0.f, 0.f, 0.f, 0.f);         \
        }                                                                    \
        gb0 = *(const int4*)(pB + (k0));                                     \
        gb1 = *(const int4*)(pB + (k0) + 8);                                 \
    }

#define STORE_TILE(bufp)                                                     \
    {                                                                        \
        _Float16* Ad = (_Float16*)(bufp);                                    \
        _Float16* Bd = (_Float16*)((char*)(bufp) + 8192);                    \
        *(f16x8*)(Ad + arow * 32 + ac) = cvt8(ga0, ga1);                     \
        *(f16x8*)(Ad + arow * 32 + ac + 8) = cvt8(ga2, ga3);                 \
        *(int4*)(Bd + arow * 32 + ac) = gb0;                                 \
        *(int4*)(Bd + arow * 32 + ac + 8) = gb1;                             \
    }

    f32x4 acc[4][4] = {};
    const int am = lane & 15;
    const int kq = (lane >> 4) * 8;  // halves

    // Prologue: tile 0 -> regs -> buf0.
    LOAD_TILE(0);
    STORE_TILE(smem);

    for (int it = 0; it < 16; ++it) {
        __syncthreads();  // buf[it&1] writes visible; vmcnt already drained
        const int cur = it & 1;
        if (it < 15) LOAD_TILE((it + 1) * 32);  // in flight until ds_write

        const _Float16* Ab = (const _Float16*)(smem + cur * 16384);
        const _Float16* Bb = (const _Float16*)(smem + cur * 16384 + 8192);

        f16x8 a[4], bb[4];
#pragma unroll
        for (int i = 0; i < 4; ++i)
            a[i] = *(const f16x8*)(Ab + (wr * 64 + i * 16 + am) * 32 + kq);
#pragma unroll
        for (int j = 0; j < 4; ++j)
            bb[j] = *(const f16x8*)(Bb + (wc * 64 + j * 16 + am) * 32 + kq);
#pragma unroll
        for (int i = 0; i < 4; ++i)
#pragma unroll
            for (int j = 0; j < 4; ++j)
                acc[i][j] = __builtin_amdgcn_mfma_f32_16x16x32_f16(
                    a[i], bb[j], acc[i][j], 0, 0, 0);

        if (it < 15) STORE_TILE(smem + (cur ^ 1) * 16384);  // vmcnt wait here
    }

    __syncthreads();  // all K-loop LDS reads done before epilogue reuse

    // Epilogue: activation into per-wave LDS tile (stride 80 halves), then
    // 16 B/lane contiguous global stores.
    const float* bias = (gate == 0) ? bz : (gate == 1) ? bfv : bo;
    _Float16* outp = (gate == 0) ? zbuf : (gate == 1) ? fbuf : obuf;
    _Float16* eb = (_Float16*)smem + wave * 5120;  // 64 x 80 halves
    const int rq = (lane >> 4) * 4;
#pragma unroll
    for (int j = 0; j < 4; ++j) {
        const int gc = n0 + wc * 64 + j * 16 + am;
        const float bj = bias[gc];
#pragma unroll
        for (int i = 0; i < 4; ++i) {
            f32x4 v = acc[i][j];
#pragma unroll
            for (int r = 0; r < 4; ++r) {
                const float val = v[r] + bj;
                const float act = (gate == 0) ? tanh_(val) : sigmoid_(val);
                eb[(i * 16 + rq + r) * 80 + j * 16 + am] = (_Float16)act;
            }
        }
    }
    __syncthreads();

    const int rrow = lane >> 3;       // 0..7
    const int rcol = (lane & 7) * 8;  // halves
#pragma unroll
    for (int rr = 0; rr < 8; ++rr) {
        const int row = rr * 8 + rrow;
        f16x8 v = *(const f16x8*)(eb + row * 80 + rcol);
        const size_t gm = (size_t)(m0 + wr * 64 + row);
        *(f16x8*)(outp + gm * DDIM + n0 + wc * 64 + rcol) = v;
    }
#undef LOAD_TILE
#undef STORE_TILE
}

// ---------------------------------------------------------------------------
// Fused single-pass scan with decoupled look-back.
// Grid: 256 blocks = (b in 8) x (chunk in 32), 256 threads = one d each.
// All 256 blocks are co-resident (1/CU) -> look-back cannot starve.
//  phase 1: per-thread chunk aggregate (A = prod f, c = local scan from 0);
//           publish to aggA/aggB (aggregate) — chunk 0 publishes inclusive.
//  look-back: walk predecessors using published aggregates; stop at first
//           inclusive. Separate aggregate (aggB) vs inclusive (aggI) arrays
//           -> no read/upgrade race. Flags via agent-scope atomics.
//  phase 2: replay chunk (z,f L2-hot) with true entering carry; h = o*c.
// ---------------------------------------------------------------------------
__global__ __launch_bounds__(256) void scan_fused(
    const _Float16* __restrict__ zbuf, const _Float16* __restrict__ fbuf,
    const _Float16* __restrict__ obuf, float* __restrict__ aggA,
    float* __restrict__ aggB, float* __restrict__ aggI,
    int* __restrict__ flags, float* __restrict__ out) {
    const int bid = blockIdx.x;       // b*NCH + chunk
    const int b = bid >> 5;
    const int chunk = bid & (NCH - 1);
    const int d = threadIdx.x;
    const size_t base = ((size_t)b * TDIM + (size_t)chunk * SCHUNK) * DDIM + d;

    // ---- phase 1: chunk aggregate ----
    float A = 1.0f, c = 0.0f;
    for (int i = 0; i < SCHUNK; i += 4) {
        float ff[4], zz[4];
#pragma unroll
        for (int u = 0; u < 4; ++u) {
            ff[u] = (float)fbuf[base + (size_t)(i + u) * DDIM];
            zz[u] = (float)zbuf[base + (size_t)(i + u) * DDIM];
        }
#pragma unroll
        for (int u = 0; u < 4; ++u) {
            A *= ff[u];
            c = ff[u] * c + (1.0f - ff[u]) * zz[u];
        }
    }

    __shared__ int st_sh;
    float c_enter = 0.0f;

    if (chunk == 0) {
        aggI[bid * 256 + d] = c;  // inclusive == local scan
        __threadfence();
        __syncthreads();
        if (d == 0)
            __hip_atomic_store(&flags[bid], 2, __ATOMIC_RELEASE,
                               __HIP_MEMORY_SCOPE_AGENT);
    } else {
        aggA[bid * 256 + d] = A;
        aggB[bid * 256 + d] = c;
        __threadfence();
        __syncthreads();
        if (d == 0)
            __hip_atomic_store(&flags[bid], 1, __ATOMIC_RELEASE,
                               __HIP_MEMORY_SCOPE_AGENT);

        // ---- look-back ----
        float accA = 1.0f, accB = 0.0f;
        for (int j = chunk - 1; j >= 0; --j) {
            if (d == 0) {
                int s;
                do {
                    s = __hip_atomic_load(&flags[(b << 5) + j],
                                          __ATOMIC_ACQUIRE,
                                          __HIP_MEMORY_SCOPE_AGENT);
                    if (s == 0) __builtin_amdgcn_s_sleep(1);
                } while (s == 0);
                st_sh = s;
            }
            __syncthreads();
            const int s = st_sh;
            __threadfence();  // make publisher's agg values visible
            if (s == 2) {
                const float v = aggI[((b << 5) + j) * 256 + d];
                c_enter = accA * v + accB;
                break;
            }
            const float Aj = aggA[((b << 5) + j) * 256 + d];
            const float Bj = aggB[((b << 5) + j) * 256 + d];
            accB = accB + accA * Bj;
            accA = accA * Aj;
            __syncthreads();  // st_sh reuse safe
        }

        // publish inclusive
        aggI[bid * 256 + d] = A * c_enter + c;
        __threadfence();
        __syncthreads();
        if (d == 0)
            __hip_atomic_store(&flags[bid], 2, __ATOMIC_RELEASE,
                               __HIP_MEMORY_SCOPE_AGENT);
    }

    // ---- phase 2: replay with true carry; h = o * c ----
    float c2 = c_enter;
    for (int i = 0; i < SCHUNK; i += 4) {
        float ff[4], zz[4], oo[4];
#pragma unroll
        for (int u = 0; u < 4; ++u) {
            ff[u] = (float)fbuf[base + (size_t)(i + u) * DDIM];
            zz[u] = (float)zbuf[base + (size_t)(i + u) * DDIM];
            oo[u] = (float)obuf[base + (size_t)(i + u) * DDIM];
        }
#pragma unroll
        for (int u = 0; u < 4; ++u) {
            c2 = ff[u] * c2 + (1.0f - ff[u]) * zz[u];
            out[base + (size_t)(i + u) * DDIM] = oo[u] * c2;
        }
    }
}

extern "C" void kernel_launch(void* const* d_in, const int* in_sizes, int n_in,
                              void* d_out, int out_size, void* d_ws,
                              size_t ws_size, hipStream_t stream) {
    const float* x = (const float*)d_in[0];
    const float* Wz = (const float*)d_in[1];
    const float* Wf = (const float*)d_in[2];
    const float* Wo = (const float*)d_in[3];
    const float* bz = (const float*)d_in[4];
    const float* bfv = (const float*)d_in[5];
    const float* bo = (const float*)d_in[6];
    float* out = (float*)d_out;

    // Workspace (bytes): Wt 0.79M | z 16.78M | f 16.78M | o 16.78M |
    // aggA 256K | aggB 256K | aggI 256K | flags 1K   -> ~51.9 MB
    char* p = (char*)d_ws;
    _Float16* Wt = (_Float16*)p;    p += (size_t)3 * 256 * 512 * 2;
    _Float16* zbuf = (_Float16*)p;  p += (size_t)MDIM * DDIM * 2;
    _Float16* fbuf = (_Float16*)p;  p += (size_t)MDIM * DDIM * 2;
    _Float16* obuf = (_Float16*)p;  p += (size_t)MDIM * DDIM * 2;
    float* aggA = (float*)p;        p += (size_t)BDIM * NCH * 256 * 4;
    float* aggB = (float*)p;        p += (size_t)BDIM * NCH * 256 * 4;
    float* aggI = (float*)p;        p += (size_t)BDIM * NCH * 256 * 4;
    int* flags = (int*)p;

    convert_w<<<(3 * 2 * 256 * 256) / 256, 256, 0, stream>>>(Wz, Wf, Wo, Wt);

    gates_mfma<<<dim3(MDIM / 128, DDIM / 128, 3), 256, 0, stream>>>(
        x, Wt, bz, bfv, bo, zbuf, fbuf, obuf);

    // zero look-back flags (d_ws is poisoned 0xAA before every launch)
    hipMemsetAsync(flags, 0, BDIM * NCH * sizeof(int), stream);

    scan_fused<<<BDIM * NCH, 256, 0, stream>>>(zbuf, fbuf, obuf, aggA, aggB,
                                               aggI, flags, out);
}